// Round 13
// baseline (139.143 us; speedup 1.0000x reference)
//
#include <hip/hip_runtime.h>
#include <hip/hip_bf16.h>
#include <stdint.h>

#define C_DIM 512
#define T_SEQ 8192
#define N_PROP 16384
#define HID_DIM 1024
#define OUT_DIM 512
#define K2C 1024  // 2*C

typedef __attribute__((ext_vector_type(8))) __bf16 bf16x8;
typedef __attribute__((ext_vector_type(4))) float f32x4;

// ---------------- fused: cumsum (blocks 0..511) + W1/W2 cvt (blocks 512..2047) ----------------
__global__ __launch_bounds__(256) void pre_kernel(const float* __restrict__ feat,
                                                  float* __restrict__ cs_inc,
                                                  const float* __restrict__ W1,
                                                  const float* __restrict__ W2,
                                                  __hip_bfloat16* __restrict__ W1b,
                                                  __hip_bfloat16* __restrict__ W2b) {
    if (blockIdx.x < C_DIM) {
        // ---- cumsum: 4 waves per channel, float4 chunks, wave scan + LDS carry ----
        int c = blockIdx.x;
        const float4* in = (const float4*)(feat + (size_t)c * T_SEQ);
        float4* out = (float4*)(cs_inc + (size_t)c * T_SEQ);
        const int lane = threadIdx.x & 63;
        const int w = threadIdx.x >> 6;
        __shared__ float wsum[4];
        float4 v[8];
        float carry = 0.0f;
#pragma unroll
        for (int i = 0; i < 8; ++i) {
            float4 t = in[w * 512 + i * 64 + lane];
            float a1 = t.x + t.y;
            float a2 = a1 + t.z;
            float a3 = a2 + t.w;
            float x = a3;
#pragma unroll
            for (int s = 1; s < 64; s <<= 1) {
                float y = __shfl_up(x, s);
                if (lane >= s) x += y;
            }
            float base = carry + (x - a3);
            v[i].x = base + t.x; v[i].y = base + a1; v[i].z = base + a2; v[i].w = base + a3;
            carry += __shfl(x, 63);
        }
        if (lane == 0) wsum[w] = carry;
        __syncthreads();
        float pre = 0.0f;
        for (int j = 0; j < 4; ++j)
            if (j < w) pre += wsum[j];
#pragma unroll
        for (int i = 0; i < 8; ++i) {
            float4 o;
            o.x = v[i].x + pre; o.y = v[i].y + pre; o.z = v[i].z + pre; o.w = v[i].w + pre;
            out[w * 512 + i * 64 + lane] = o;
        }
    } else {
        // ---- fp32 -> bf16 convert ----
        const int n1 = HID_DIM * K2C;
        int i = ((blockIdx.x - C_DIM) * 256 + threadIdx.x) * 4;
        const float* src;
        __hip_bfloat16* dst;
        int j;
        if (i < n1) { src = W1; dst = W1b; j = i; }
        else        { src = W2; dst = W2b; j = i - n1; }
        float4 v = *(const float4*)(src + j);
        __hip_bfloat16 h0 = __float2bfloat16(v.x);
        __hip_bfloat16 h1 = __float2bfloat16(v.y);
        __hip_bfloat16 h2 = __float2bfloat16(v.z);
        __hip_bfloat16 h3 = __float2bfloat16(v.w);
        ushort4 u;
        u.x = *(unsigned short*)&h0; u.y = *(unsigned short*)&h1;
        u.z = *(unsigned short*)&h2; u.w = *(unsigned short*)&h3;
        *(ushort4*)(dst + j) = u;
    }
}

// ---------------- transpose cs_inc (C, T) -> cs_t (T+1, C) with leading-zero shift ----------------
__global__ __launch_bounds__(256) void transpose_kernel(const float* __restrict__ cs_inc,
                                                        float* __restrict__ cs_t) {
    __shared__ float tl[32][33];
    int tx = threadIdx.x, ty = threadIdx.y;  // (32, 8)
    int x0 = blockIdx.x * 32;
    int y0 = blockIdx.y * 32;
#pragma unroll
    for (int i = 0; i < 32; i += 8) {
        int t = x0 + tx;
        int ch = y0 + ty + i;
        float v = 0.0f;
        if (t >= 1 && t <= T_SEQ) v = cs_inc[(size_t)ch * T_SEQ + (t - 1)];
        tl[ty + i][tx] = v;
    }
    __syncthreads();
#pragma unroll
    for (int i = 0; i < 32; i += 8) {
        int t = x0 + ty + i;
        int ch = y0 + tx;
        if (t <= T_SEQ) cs_t[(size_t)t * C_DIM + ch] = tl[tx][ty + i];
    }
}

// ---------------- pooling -> e (N, 2C) bf16; 4 proposals/block, float4/thread ----------------
__global__ __launch_bounds__(512) void pool_kernel(const float* __restrict__ cs_t,
                                                   const int* __restrict__ lptr,
                                                   const int* __restrict__ rptr,
                                                   __hip_bfloat16* __restrict__ e) {
    int n = blockIdx.x * 4 + (threadIdx.x >> 7);
    int c4 = (threadIdx.x & 127) * 4;
    int li = lptr[n], ri = rptr[n];
    float w = fmaxf((float)(ri - li), 1.0f);
    int bw = max(1, (int)(0.15f * w));
    int lb_s = max(0, li - bw);
    int lb_e = min(T_SEQ, li + bw);
    int rb_s = max(0, ri - bw);
    int rb_e = min(T_SEQ, ri + bw);
    lb_e = min(max(lb_s + 1, lb_e), T_SEQ);
    rb_e = min(max(rb_s + 1, rb_e), T_SEQ);
    float4 a = *(const float4*)(cs_t + (size_t)lb_e * C_DIM + c4);
    float4 b = *(const float4*)(cs_t + (size_t)lb_s * C_DIM + c4);
    float4 cc = *(const float4*)(cs_t + (size_t)rb_e * C_DIM + c4);
    float4 d = *(const float4*)(cs_t + (size_t)rb_s * C_DIM + c4);
    float rl = 1.0f / (float)(lb_e - lb_s);
    float rr = 1.0f / (float)(rb_e - rb_s);
    __hip_bfloat16 L0 = __float2bfloat16((a.x - b.x) * rl);
    __hip_bfloat16 L1 = __float2bfloat16((a.y - b.y) * rl);
    __hip_bfloat16 L2 = __float2bfloat16((a.z - b.z) * rl);
    __hip_bfloat16 L3 = __float2bfloat16((a.w - b.w) * rl);
    __hip_bfloat16 R0 = __float2bfloat16((cc.x - d.x) * rr);
    __hip_bfloat16 R1 = __float2bfloat16((cc.y - d.y) * rr);
    __hip_bfloat16 R2 = __float2bfloat16((cc.z - d.z) * rr);
    __hip_bfloat16 R3 = __float2bfloat16((cc.w - d.w) * rr);
    ushort4 ul, ur;
    ul.x = *(unsigned short*)&L0; ul.y = *(unsigned short*)&L1;
    ul.z = *(unsigned short*)&L2; ul.w = *(unsigned short*)&L3;
    ur.x = *(unsigned short*)&R0; ur.y = *(unsigned short*)&R1;
    ur.z = *(unsigned short*)&R2; ur.w = *(unsigned short*)&R3;
    *(ushort4*)(e + (size_t)n * K2C + c4) = ul;
    *(ushort4*)(e + (size_t)n * K2C + C_DIM + c4) = ur;
}

// ---------------- big-wave-tile GEMM (LDS-BW roofline design) ----------------
// C[m][n] = sum_k A[m][k]*B[n][k] (+bias, optional relu->bf16). BK=64.
// R6/R10 measured ~100 B/cy/CU LDS traffic = the roofline. Lever: FLOP per LDS byte.
// 256 thr = 4 waves (2x2); wave tile 128 x (BN/2). GEMM1 (BN=256): wave 128x128 ->
// 65 FLOP/LDS-byte (vs 44 at 128x64); per-CU-tile LDS = 4x32KB reads + 64KB writes
// = 192 KB (R10: 352 KB per equal output). acc 256 VGPR + frags ~340 -> 1 wave/SIMD
// (__launch_bounds__(256,1)); occupancy is irrelevant at an LDS-BW roofline.
// Loop = R10-proven race-free 2-phase: stage(t+1 -> cur^1) FIRST, ds_read(cur),
// MFMA, __syncthreads. 2-slot ring WAR argument as in R6/R10.
// Swizzle: proven granule-XOR both-sides (0 conflicts). XCD swizzle (grid 256).
template <int BM, int BN, int K, int RELU_BF16>
__global__ __launch_bounds__(256, 1) void gemm_bw_kernel(const __hip_bfloat16* __restrict__ A,
                                                         const __hip_bfloat16* __restrict__ B,
                                                         const float* __restrict__ bias,
                                                         void* __restrict__ Cout,
                                                         int Nc, int NBlk) {
    constexpr int BK = 64;
    constexpr int NT = K / BK;
    constexpr int WMT = BM / 2, WNT = BN / 2;  // wave tile
    constexpr int MR = WMT / 16, NR = WNT / 16;
    constexpr int RA = BM / 32, RB = BN / 32;  // staging calls (32 rows each)

    __shared__ __align__(16) __hip_bfloat16 As[2][BM * BK];
    __shared__ __align__(16) __hip_bfloat16 Bs[2][BN * BK];

    const int tid = threadIdx.x;
    const int lane = tid & 63;
    const int wid = tid >> 6;
    const int wm = wid >> 1, wn = wid & 1;

    const int nwg = gridDim.x;  // 256 (multiple of 8)
    const int wg = (blockIdx.x & 7) * (nwg >> 3) + (blockIdx.x >> 3);
    const long m0 = (long)(wg / NBlk) * BM;
    const long n0 = (long)(wg % NBlk) * BN;

    const int srow = tid >> 3;                  // 32 rows per staging call
    const int schunk = (tid & 7) ^ (srow & 7);  // pre-swizzled 16B source granule
    const int fr = lane & 15;
    const int g8 = (lane >> 4) * 8;

    f32x4 acc[MR][NR] = {};

    auto stage = [&](int s, long k0) {
#pragma unroll
        for (int i = 0; i < RA; ++i)
            __builtin_amdgcn_global_load_lds(
                (const __attribute__((address_space(1))) void*)(A + (m0 + i * 32 + srow) * K + k0 + schunk * 8),
                (__attribute__((address_space(3))) void*)(&As[s][i * 2048 + tid * 8]), 16, 0, 0);
#pragma unroll
        for (int i = 0; i < RB; ++i)
            __builtin_amdgcn_global_load_lds(
                (const __attribute__((address_space(1))) void*)(B + (n0 + i * 32 + srow) * K + k0 + schunk * 8),
                (__attribute__((address_space(3))) void*)(&Bs[s][i * 2048 + tid * 8]), 16, 0, 0);
    };
    auto ldA = [&](int s, int row, int kb) -> bf16x8 {
        return *(const bf16x8*)(&As[s][row * BK + ((kb + g8) ^ ((row & 7) * 8))]);
    };
    auto ldB = [&](int s, int row, int kb) -> bf16x8 {
        return *(const bf16x8*)(&Bs[s][row * BK + ((kb + g8) ^ ((row & 7) * 8))]);
    };

    stage(0, 0);
    __syncthreads();
    for (int t = 0; t < NT; ++t) {
        const int cur = t & 1;
        if (t + 1 < NT) stage(cur ^ 1, (long)(t + 1) * BK);
#pragma unroll
        for (int kk = 0; kk < 2; ++kk) {
            bf16x8 af[MR], bv[NR];
#pragma unroll
            for (int m = 0; m < MR; ++m) af[m] = ldA(cur, wm * WMT + m * 16 + fr, kk * 32);
#pragma unroll
            for (int n = 0; n < NR; ++n) bv[n] = ldB(cur, wn * WNT + n * 16 + fr, kk * 32);
#pragma unroll
            for (int m = 0; m < MR; ++m)
#pragma unroll
                for (int n = 0; n < NR; ++n)
                    acc[m][n] = __builtin_amdgcn_mfma_f32_16x16x32_bf16(af[m], bv[n], acc[m][n], 0, 0, 0);
        }
        __syncthreads();
    }

    const int rq = (lane >> 4) * 4;
#pragma unroll
    for (int m = 0; m < MR; ++m)
#pragma unroll
        for (int n = 0; n < NR; ++n) {
            long col = n0 + wn * WNT + n * 16 + fr;
            float bb = bias[col];
#pragma unroll
            for (int q = 0; q < 4; ++q) {
                long row = m0 + wm * WMT + m * 16 + rq + q;
                float v = acc[m][n][q] + bb;
                if (RELU_BF16) {
                    v = fmaxf(v, 0.0f);
                    ((__hip_bfloat16*)Cout)[row * Nc + col] = __float2bfloat16(v);
                } else {
                    ((float*)Cout)[row * Nc + col] = v;
                }
            }
        }
}

extern "C" void kernel_launch(void* const* d_in, const int* in_sizes, int n_in,
                              void* d_out, int out_size, void* d_ws, size_t ws_size,
                              hipStream_t stream) {
    const float* feat = (const float*)d_in[0];
    const int* l = (const int*)d_in[1];
    const int* r = (const int*)d_in[2];
    const float* W1 = (const float*)d_in[4];
    const float* b1 = (const float*)d_in[5];
    const float* W2 = (const float*)d_in[6];
    const float* b2 = (const float*)d_in[7];

    char* ws = (char*)d_ws;
    float* cs_t = (float*)ws;                                    // 8193*512*4
    __hip_bfloat16* e = (__hip_bfloat16*)(ws + 16779264);        // 16384*1024*2
    __hip_bfloat16* h = (__hip_bfloat16*)(ws + 50333696);        // 16384*1024*2 (aliases cs_inc)
    float* cs_inc = (float*)(ws + 50333696);                     // 512*8192*4, dead before h
    __hip_bfloat16* W1b = (__hip_bfloat16*)(ws + 83888128);      // 1024*1024*2
    __hip_bfloat16* W2b = (__hip_bfloat16*)(ws + 85985280);      // 512*1024*2

    const int ncvt = (HID_DIM * K2C + OUT_DIM * HID_DIM) / 4 / 256;  // 1536
    pre_kernel<<<dim3(C_DIM + ncvt), 256, 0, stream>>>(feat, cs_inc, W1, W2, W1b, W2b);
    transpose_kernel<<<dim3((T_SEQ + 32) / 32, C_DIM / 32), dim3(32, 8), 0, stream>>>(cs_inc, cs_t);
    pool_kernel<<<dim3(N_PROP / 4), 512, 0, stream>>>(cs_t, l, r, e);

    // GEMM1: h = relu(e @ W1^T + b1). 256x256 tile, 4 waves (wave 128x128), 256 blocks.
    gemm_bw_kernel<256, 256, K2C, 1>
        <<<dim3((N_PROP / 256) * (HID_DIM / 256)), 256, 0, stream>>>(e, W1b, b1, h, HID_DIM, HID_DIM / 256);
    // GEMM2: out = h @ W2^T + b2. 256x128 tile, 4 waves (wave 128x64), 256 blocks.
    gemm_bw_kernel<256, 128, HID_DIM, 0>
        <<<dim3((N_PROP / 256) * (OUT_DIM / 128)), 256, 0, stream>>>(h, W2b, b2, d_out, OUT_DIM, OUT_DIM / 128);
}

// Round 14
// 104.941 us; speedup vs baseline: 1.3259x; 1.3259x over previous
//
#include <hip/hip_runtime.h>
#include <hip/hip_bf16.h>
#include <stdint.h>

#define C_DIM 512
#define T_SEQ 8192
#define N_PROP 16384
#define HID_DIM 1024
#define OUT_DIM 512
#define K2C 1024  // 2*C

typedef __attribute__((ext_vector_type(8))) __bf16 bf16x8;
typedef __attribute__((ext_vector_type(4))) float f32x4;

// ---------------- fused: cumsum (blocks 0..511, 4 waves/channel) + W1/W2 cvt ----------------
__global__ __launch_bounds__(256) void pre_kernel(const float* __restrict__ feat,
                                                  float* __restrict__ cs_inc,
                                                  const float* __restrict__ W1,
                                                  const float* __restrict__ W2,
                                                  __hip_bfloat16* __restrict__ W1b,
                                                  __hip_bfloat16* __restrict__ W2b) {
    if (blockIdx.x < C_DIM) {
        int c = blockIdx.x;
        const float4* in = (const float4*)(feat + (size_t)c * T_SEQ);
        float4* out = (float4*)(cs_inc + (size_t)c * T_SEQ);
        const int lane = threadIdx.x & 63;
        const int w = threadIdx.x >> 6;
        __shared__ float wsum[4];
        float4 v[8];
        float carry = 0.0f;
#pragma unroll
        for (int i = 0; i < 8; ++i) {
            float4 t = in[w * 512 + i * 64 + lane];
            float a1 = t.x + t.y;
            float a2 = a1 + t.z;
            float a3 = a2 + t.w;
            float x = a3;
#pragma unroll
            for (int s = 1; s < 64; s <<= 1) {
                float y = __shfl_up(x, s);
                if (lane >= s) x += y;
            }
            float base = carry + (x - a3);
            v[i].x = base + t.x; v[i].y = base + a1; v[i].z = base + a2; v[i].w = base + a3;
            carry += __shfl(x, 63);
        }
        if (lane == 0) wsum[w] = carry;
        __syncthreads();
        float pre = 0.0f;
        for (int j = 0; j < 4; ++j)
            if (j < w) pre += wsum[j];
#pragma unroll
        for (int i = 0; i < 8; ++i) {
            float4 o;
            o.x = v[i].x + pre; o.y = v[i].y + pre; o.z = v[i].z + pre; o.w = v[i].w + pre;
            out[w * 512 + i * 64 + lane] = o;
        }
    } else {
        const int n1 = HID_DIM * K2C;
        int i = ((blockIdx.x - C_DIM) * 256 + threadIdx.x) * 4;
        const float* src;
        __hip_bfloat16* dst;
        int j;
        if (i < n1) { src = W1; dst = W1b; j = i; }
        else        { src = W2; dst = W2b; j = i - n1; }
        float4 v = *(const float4*)(src + j);
        __hip_bfloat16 h0 = __float2bfloat16(v.x);
        __hip_bfloat16 h1 = __float2bfloat16(v.y);
        __hip_bfloat16 h2 = __float2bfloat16(v.z);
        __hip_bfloat16 h3 = __float2bfloat16(v.w);
        ushort4 u;
        u.x = *(unsigned short*)&h0; u.y = *(unsigned short*)&h1;
        u.z = *(unsigned short*)&h2; u.w = *(unsigned short*)&h3;
        *(ushort4*)(dst + j) = u;
    }
}

// ---------------- transpose cs_inc (C, T) -> cs_t (T+1, C) with leading-zero shift ----------------
__global__ __launch_bounds__(256) void transpose_kernel(const float* __restrict__ cs_inc,
                                                        float* __restrict__ cs_t) {
    __shared__ float tl[32][33];
    int tx = threadIdx.x, ty = threadIdx.y;  // (32, 8)
    int x0 = blockIdx.x * 32;
    int y0 = blockIdx.y * 32;
#pragma unroll
    for (int i = 0; i < 32; i += 8) {
        int t = x0 + tx;
        int ch = y0 + ty + i;
        float v = 0.0f;
        if (t >= 1 && t <= T_SEQ) v = cs_inc[(size_t)ch * T_SEQ + (t - 1)];
        tl[ty + i][tx] = v;
    }
    __syncthreads();
#pragma unroll
    for (int i = 0; i < 32; i += 8) {
        int t = x0 + ty + i;
        int ch = y0 + tx;
        if (t <= T_SEQ) cs_t[(size_t)t * C_DIM + ch] = tl[tx][ty + i];
    }
}

// ---------------- pooling -> e (N, 2C) bf16; 4 proposals/block, float4/thread ----------------
__global__ __launch_bounds__(512) void pool_kernel(const float* __restrict__ cs_t,
                                                   const int* __restrict__ lptr,
                                                   const int* __restrict__ rptr,
                                                   __hip_bfloat16* __restrict__ e) {
    int n = blockIdx.x * 4 + (threadIdx.x >> 7);
    int c4 = (threadIdx.x & 127) * 4;
    int li = lptr[n], ri = rptr[n];
    float w = fmaxf((float)(ri - li), 1.0f);
    int bw = max(1, (int)(0.15f * w));
    int lb_s = max(0, li - bw);
    int lb_e = min(T_SEQ, li + bw);
    int rb_s = max(0, ri - bw);
    int rb_e = min(T_SEQ, ri + bw);
    lb_e = min(max(lb_s + 1, lb_e), T_SEQ);
    rb_e = min(max(rb_s + 1, rb_e), T_SEQ);
    float4 a = *(const float4*)(cs_t + (size_t)lb_e * C_DIM + c4);
    float4 b = *(const float4*)(cs_t + (size_t)lb_s * C_DIM + c4);
    float4 cc = *(const float4*)(cs_t + (size_t)rb_e * C_DIM + c4);
    float4 d = *(const float4*)(cs_t + (size_t)rb_s * C_DIM + c4);
    float rl = 1.0f / (float)(lb_e - lb_s);
    float rr = 1.0f / (float)(rb_e - rb_s);
    __hip_bfloat16 L0 = __float2bfloat16((a.x - b.x) * rl);
    __hip_bfloat16 L1 = __float2bfloat16((a.y - b.y) * rl);
    __hip_bfloat16 L2 = __float2bfloat16((a.z - b.z) * rl);
    __hip_bfloat16 L3 = __float2bfloat16((a.w - b.w) * rl);
    __hip_bfloat16 R0 = __float2bfloat16((cc.x - d.x) * rr);
    __hip_bfloat16 R1 = __float2bfloat16((cc.y - d.y) * rr);
    __hip_bfloat16 R2 = __float2bfloat16((cc.z - d.z) * rr);
    __hip_bfloat16 R3 = __float2bfloat16((cc.w - d.w) * rr);
    ushort4 ul, ur;
    ul.x = *(unsigned short*)&L0; ul.y = *(unsigned short*)&L1;
    ul.z = *(unsigned short*)&L2; ul.w = *(unsigned short*)&L3;
    ur.x = *(unsigned short*)&R0; ur.y = *(unsigned short*)&R1;
    ur.z = *(unsigned short*)&R2; ur.w = *(unsigned short*)&R3;
    *(ushort4*)(e + (size_t)n * K2C + c4) = ul;
    *(ushort4*)(e + (size_t)n * K2C + C_DIM + c4) = ur;
}

// ---------------- R8 GEMM verbatim (best wall: 112.88): BK=64, ring-NSLOT, 1 wait/tile ----------------
// C[m][n] = sum_k A[m][k]*B[n][k] (+bias, optional relu->bf16). 512 thr = 8 waves (WM x WN).
// Per tile u (cur = u % NSLOT):
//   ds_read frags | MFMA (setprio) | s_barrier | stage tile u+NSLOT into cur (WAR-safe)
//   | own counted vmcnt | s_barrier (wait-then-barrier publish discipline).
// GEMM1: 256x256 NSLOT=2 (LDS 128KB); GEMM2: 256x128 NSLOT=3 (144KB).
// Swizzle: 8-granule XOR both-sides (0 conflicts). XCD swizzle (grid 256).
template <int BM, int BN, int WM, int WN, int NSLOT, int K, int RELU_BF16>
__global__ __launch_bounds__(512, 2) void gemm_dp_kernel(const __hip_bfloat16* __restrict__ A,
                                                         const __hip_bfloat16* __restrict__ B,
                                                         const float* __restrict__ bias,
                                                         void* __restrict__ Cout,
                                                         int Nc, int NBlk) {
    constexpr int BK = 64;
    constexpr int NT = K / BK;
    constexpr int WMT = BM / WM, WNT = BN / WN;
    constexpr int MR = WMT / 16, NR = WNT / 16;
    constexpr int LA = BM / 64, LB = BN / 64;
    constexpr int LPT = LA + LB;

    __shared__ __align__(16) __hip_bfloat16 As[NSLOT][BM * BK];
    __shared__ __align__(16) __hip_bfloat16 Bs[NSLOT][BN * BK];

    const int tid = threadIdx.x;
    const int lane = tid & 63;
    const int wid = tid >> 6;
    const int wm = wid / WN;
    const int wn = wid % WN;

    const int nwg = gridDim.x;  // 256
    const int wg = (blockIdx.x & 7) * (nwg >> 3) + (blockIdx.x >> 3);
    const long m0 = (long)(wg / NBlk) * BM;
    const long n0 = (long)(wg % NBlk) * BN;

    const int srow = tid >> 3;
    const int schunk = (tid & 7) ^ (srow & 7);
    const int fr = lane & 15;
    const int g8 = (lane >> 4) * 8;

    f32x4 acc[MR][NR] = {};

    auto stage = [&](int s, int k0) {
#pragma unroll
        for (int i = 0; i < LA; ++i)
            __builtin_amdgcn_global_load_lds(
                (const __attribute__((address_space(1))) void*)(A + (m0 + i * 64 + srow) * K + k0 + schunk * 8),
                (__attribute__((address_space(3))) void*)(&As[s][i * 4096 + tid * 8]), 16, 0, 0);
#pragma unroll
        for (int i = 0; i < LB; ++i)
            __builtin_amdgcn_global_load_lds(
                (const __attribute__((address_space(1))) void*)(B + (n0 + i * 64 + srow) * K + k0 + schunk * 8),
                (__attribute__((address_space(3))) void*)(&Bs[s][i * 4096 + tid * 8]), 16, 0, 0);
    };
    auto ldA = [&](int s, int row, int kbase) -> bf16x8 {
        return *(const bf16x8*)(&As[s][row * BK + ((kbase + g8) ^ ((row & 7) * 8))]);
    };
    auto ldB = [&](int s, int row, int kbase) -> bf16x8 {
        return *(const bf16x8*)(&Bs[s][row * BK + ((kbase + g8) ^ ((row & 7) * 8))]);
    };

    // prologue: fill the ring; publish tile 0 (own-wait -> barrier)
#pragma unroll
    for (int s = 0; s < NSLOT; ++s) stage(s, s * BK);
    asm volatile("s_waitcnt vmcnt(%0)" ::"n"(LPT * (NSLOT - 1)) : "memory");
    __builtin_amdgcn_s_barrier();

    for (int u = 0; u < NT; ++u) {
        const int cur = u % NSLOT;
        bf16x8 af[MR], bv[NR];
        // ---- kk0 ----
#pragma unroll
        for (int m = 0; m < MR; ++m) af[m] = ldA(cur, wm * WMT + m * 16 + fr, 0);
#pragma unroll
        for (int n = 0; n < NR; ++n) bv[n] = ldB(cur, wn * WNT + n * 16 + fr, 0);
        __builtin_amdgcn_s_setprio(1);
#pragma unroll
        for (int m = 0; m < MR; ++m)
#pragma unroll
            for (int n = 0; n < NR; ++n)
                acc[m][n] = __builtin_amdgcn_mfma_f32_16x16x32_bf16(af[m], bv[n], acc[m][n], 0, 0, 0);
        __builtin_amdgcn_s_setprio(0);
        // ---- kk1 ----
#pragma unroll
        for (int m = 0; m < MR; ++m) af[m] = ldA(cur, wm * WMT + m * 16 + fr, 32);
#pragma unroll
        for (int n = 0; n < NR; ++n) bv[n] = ldB(cur, wn * WNT + n * 16 + fr, 32);
        __builtin_amdgcn_s_setprio(1);
#pragma unroll
        for (int m = 0; m < MR; ++m)
#pragma unroll
            for (int n = 0; n < NR; ++n)
                acc[m][n] = __builtin_amdgcn_mfma_f32_16x16x32_bf16(af[m], bv[n], acc[m][n], 0, 0, 0);
        __builtin_amdgcn_s_setprio(0);

        __builtin_amdgcn_s_barrier();  // all waves' reads of slot cur complete
        if (u + NSLOT < NT) stage(cur, (u + NSLOT) * BK);  // WAR-safe overwrite of cur
        // publish tile u+1: own counted wait, then shared barrier
        if (u + 1 < NT) {
            if (u + NSLOT < NT)
                asm volatile("s_waitcnt vmcnt(%0)" ::"n"(LPT * (NSLOT - 1)) : "memory");
            else if (NSLOT == 3 && u + 2 < NT)
                asm volatile("s_waitcnt vmcnt(%0)" ::"n"(LPT) : "memory");
            else
                asm volatile("s_waitcnt vmcnt(0)" ::: "memory");
            __builtin_amdgcn_s_barrier();
        }
    }

    const int rq = (lane >> 4) * 4;
#pragma unroll
    for (int m = 0; m < MR; ++m)
#pragma unroll
        for (int n = 0; n < NR; ++n) {
            long col = n0 + wn * WNT + n * 16 + fr;
            float bb = bias[col];
#pragma unroll
            for (int q = 0; q < 4; ++q) {
                long row = m0 + wm * WMT + m * 16 + rq + q;
                float v = acc[m][n][q] + bb;
                if (RELU_BF16) {
                    v = fmaxf(v, 0.0f);
                    ((__hip_bfloat16*)Cout)[row * Nc + col] = __float2bfloat16(v);
                } else {
                    ((float*)Cout)[row * Nc + col] = v;
                }
            }
        }
}

extern "C" void kernel_launch(void* const* d_in, const int* in_sizes, int n_in,
                              void* d_out, int out_size, void* d_ws, size_t ws_size,
                              hipStream_t stream) {
    const float* feat = (const float*)d_in[0];
    const int* l = (const int*)d_in[1];
    const int* r = (const int*)d_in[2];
    const float* W1 = (const float*)d_in[4];
    const float* b1 = (const float*)d_in[5];
    const float* W2 = (const float*)d_in[6];
    const float* b2 = (const float*)d_in[7];

    char* ws = (char*)d_ws;
    float* cs_t = (float*)ws;                                    // 8193*512*4
    __hip_bfloat16* e = (__hip_bfloat16*)(ws + 16779264);        // 16384*1024*2
    __hip_bfloat16* h = (__hip_bfloat16*)(ws + 50333696);        // 16384*1024*2 (aliases cs_inc)
    float* cs_inc = (float*)(ws + 50333696);                     // 512*8192*4, dead before h
    __hip_bfloat16* W1b = (__hip_bfloat16*)(ws + 83888128);      // 1024*1024*2
    __hip_bfloat16* W2b = (__hip_bfloat16*)(ws + 85985280);      // 512*1024*2

    const int ncvt = (HID_DIM * K2C + OUT_DIM * HID_DIM) / 4 / 256;  // 1536
    pre_kernel<<<dim3(C_DIM + ncvt), 256, 0, stream>>>(feat, cs_inc, W1, W2, W1b, W2b);
    transpose_kernel<<<dim3((T_SEQ + 32) / 32, C_DIM / 32), dim3(32, 8), 0, stream>>>(cs_inc, cs_t);
    pool_kernel<<<dim3(N_PROP / 4), 512, 0, stream>>>(cs_t, l, r, e);

    // GEMM1: h = relu(e @ W1^T + b1). 256x256, BK=64, 2-slot ring, 256 blocks.
    gemm_dp_kernel<256, 256, 2, 4, 2, K2C, 1>
        <<<dim3((N_PROP / 256) * (HID_DIM / 256)), 512, 0, stream>>>(e, W1b, b1, h, HID_DIM, HID_DIM / 256);
    // GEMM2: out = h @ W2^T + b2. 256x128, BK=64, 3-slot ring, 256 blocks.
    gemm_dp_kernel<256, 128, 4, 2, 3, HID_DIM, 0>
        <<<dim3((N_PROP / 256) * (OUT_DIM / 128)), 512, 0, stream>>>(h, W2b, b2, d_out, OUT_DIM, OUT_DIM / 128);
}